// Round 13
// baseline (1921.145 us; speedup 1.0000x reference)
//
#include <hip/hip_runtime.h>
#include <math.h>

// TransitionNER head:  hidden = tanh(concat(4x[B,1024]) @ W1 + b1)
//                      logits = hidden @ W2 + b2 ; masked log-softmax ; argmax + gold gather
// B=16384, H=1024, A=20, K=4096.
//
// Round 13: revert to r11 gemm (451us, 16x16x32 — r12's 32x32 shape is inherently
// 4-way LDS-bank-aliased at 128B row stride; conflicts 8.4M->33.5M explained the
// +57us). Two additive fixes, same barrier structure:
//  1. B-locality mapping: nt=(bid&7)&3, mt=(bid>>3)+32*((bid&7)>>2) -> each XCD
//     serves ONE nt => its 4MB B-image pair is L2-resident (was 16MB thrash to L3;
//     ~2GB fabric traffic -> ~0.3GB).
//  2. Depth-2 A-reg pipeline: A(k+1) regs loaded one step early (landed via the
//     prior __syncthreads vmcnt drain), split8+ds_write moved from step TAIL to
//     HEAD -> drains under MFMAs. Named reg sets, unroll x2. Bit-identical numerics.
// head/refine/wpack/detect unchanged.

#define BTOT 16384
#define HD   1024
#define NACT 20
#define KTOT 4096
#define KT_N 128          // number of 32-wide k tiles

typedef __attribute__((ext_vector_type(8))) short short8;
typedef __attribute__((ext_vector_type(4))) float f32x4;

#define MFMA(a, b, c) __builtin_amdgcn_mfma_f32_16x16x32_bf16((a), (b), (c), 0, 0, 0)

// ---------------- global -> LDS direct load (16B) ----------------
__device__ __forceinline__ void gload16(const void* g, void* l)
{
    auto gp = (const __attribute__((address_space(1))) unsigned int*)((uintptr_t)g);
    auto lp = (__attribute__((address_space(3))) unsigned int*)((uintptr_t)l);
    __builtin_amdgcn_global_load_lds(gp, lp, 16, 0, 0);
}

// ---------------- bf16 split helpers (RNE) ----------------
__device__ __forceinline__ void split8(const float4 v0, const float4 v1,
                                       int4& hi, int4& lo)
{
    const float f[8] = {v0.x, v0.y, v0.z, v0.w, v1.x, v1.y, v1.z, v1.w};
    unsigned hp[4], lp[4];
#pragma unroll
    for (int i = 0; i < 4; ++i) {
        const unsigned u0 = __float_as_uint(f[2 * i]);
        const unsigned u1 = __float_as_uint(f[2 * i + 1]);
        const unsigned r0 = u0 + 0x7FFFu + ((u0 >> 16) & 1u);
        const unsigned r1 = u1 + 0x7FFFu + ((u1 >> 16) & 1u);
        hp[i] = (r0 >> 16) | (r1 & 0xFFFF0000u);
        const float h0 = __uint_as_float(r0 & 0xFFFF0000u);
        const float h1 = __uint_as_float(r1 & 0xFFFF0000u);
        const float d0 = f[2 * i] - h0;
        const float d1 = f[2 * i + 1] - h1;
        const unsigned s0 = __float_as_uint(d0);
        const unsigned s1 = __float_as_uint(d1);
        const unsigned q0 = s0 + 0x7FFFu + ((s0 >> 16) & 1u);
        const unsigned q1 = s1 + 0x7FFFu + ((s1 >> 16) & 1u);
        lp[i] = (q0 >> 16) | (q1 & 0xFFFF0000u);
    }
    hi = make_int4((int)hp[0], (int)hp[1], (int)hp[2], (int)hp[3]);
    lo = make_int4((int)lp[0], (int)lp[1], (int)lp[2], (int)lp[3]);
}

// ---------------- mask dtype detection ----------------
__global__ __launch_bounds__(256) void detect_mask_kernel(
    const unsigned int* __restrict__ w, int nwords, int* __restrict__ ctr)
{
    int c0 = 0, c1 = 0, c2 = 0, c3 = 0;
    for (int i = blockIdx.x * 256 + threadIdx.x; i < nwords; i += gridDim.x * 256) {
        unsigned int v = w[i];
        c0 += (v & 0x000000FFu) ? 1 : 0;
        c1 += (v & 0x0000FF00u) ? 1 : 0;
        c2 += (v & 0x00FF0000u) ? 1 : 0;
        c3 += (v & 0xFF000000u) ? 1 : 0;
    }
#pragma unroll
    for (int off = 32; off; off >>= 1) {
        c0 += __shfl_xor(c0, off, 64);
        c1 += __shfl_xor(c1, off, 64);
        c2 += __shfl_xor(c2, off, 64);
        c3 += __shfl_xor(c3, off, 64);
    }
    if ((threadIdx.x & 63) == 0) {
        atomicAdd(&ctr[0], c0);
        atomicAdd(&ctr[1], c1);
        atomicAdd(&ctr[2], c2);
        atomicAdd(&ctr[3], c3);
    }
}

// ---------------- W pack: [K][N] f32 -> swizzled bf16 hi/lo tile images ----------------
__global__ __launch_bounds__(256) void wpack_kernel(
    const float* __restrict__ W1, char* __restrict__ Wp)
{
    const int b  = blockIdx.x;
    const int t  = threadIdx.x;
    const int nt = b >> 7;
    const int kt = b & 127;
    const int nn = t & 127;
    const int h  = t >> 7;

    float f[16];
#pragma unroll
    for (int kk = 0; kk < 16; ++kk)
        f[kk] = W1[(size_t)(kt * 32 + h * 16 + kk) * HD + nt * 128 + nn];

    int4 hi0, lo0, hi1, lo1;
    split8(make_float4(f[0], f[1], f[2], f[3]),
           make_float4(f[4], f[5], f[6], f[7]), hi0, lo0);
    split8(make_float4(f[8], f[9], f[10], f[11]),
           make_float4(f[12], f[13], f[14], f[15]), hi1, lo1);

    char* rowp = Wp + (((size_t)(nt * KT_N + kt)) << 14) + nn * 128;
    const int r7 = nn & 7;
    const int s0 = ((2 * h) ^ r7) << 4;
    const int s1 = ((2 * h + 1) ^ r7) << 4;
    *(int4*)(rowp + s0)        = hi0;
    *(int4*)(rowp + s1)        = hi1;
    *(int4*)(rowp + (s0 ^ 64)) = lo0;
    *(int4*)(rowp + (s1 ^ 64)) = lo1;
}

// ---------------- GEMM1: 256x256 tile, 8 waves, staggered 3-pass MFMA ----------------
// grid = 256 blocks (1/CU). LDS 128KB dynamic: [buf][A 32K | B 32K].

// One phase = one A-fragment pair (mf = 2*AP, 2*AP+1) x all 4 B-frags, 3-pass.
#define PHASE(AP)                                                                   \
    {                                                                               \
        const short8 ah0 = *(const short8*)(bufc + (aBase + (2*(AP)) * 2048));      \
        const short8 al0 = *(const short8*)(bufc + ((aBase + (2*(AP)) * 2048) ^ 64)); \
        const short8 ah1 = *(const short8*)(bufc + (aBase + (2*(AP)+1) * 2048));    \
        const short8 al1 = *(const short8*)(bufc + ((aBase + (2*(AP)+1) * 2048) ^ 64)); \
        __builtin_amdgcn_s_setprio(1);                                              \
        _Pragma("unroll")                                                           \
        for (int nf = 0; nf < 4; ++nf) {                                            \
            acc[2*(AP)][nf]   = MFMA(ah0, bh[nf], acc[2*(AP)][nf]);                 \
            acc[2*(AP)][nf]   = MFMA(ah0, bl[nf], acc[2*(AP)][nf]);                 \
            acc[2*(AP)][nf]   = MFMA(al0, bh[nf], acc[2*(AP)][nf]);                 \
            acc[2*(AP)+1][nf] = MFMA(ah1, bh[nf], acc[2*(AP)+1][nf]);               \
            acc[2*(AP)+1][nf] = MFMA(ah1, bl[nf], acc[2*(AP)+1][nf]);               \
            acc[2*(AP)+1][nf] = MFMA(al1, bh[nf], acc[2*(AP)+1][nf]);               \
        }                                                                           \
        __builtin_amdgcn_s_setprio(0);                                              \
    }

// One K-step. CUR holds A(KT+1) f32 data (loaded >=1 barrier ago -> landed).
// Issues A(KT+2) into NXT; split+write of A(KT+1) at step HEAD (drains under MFMA).
#define STEP(KT, CUR, NXT)                                                          \
    {                                                                               \
        const int curb = (KT) & 1;                                                  \
        const char* bufc  = smem + curb * 65536;                                    \
        const char* bufcB = bufc + 32768;                                           \
        char*       bufn  = smem + (curb ^ 1) * 65536;                              \
        if ((KT) + 2 < KT_N) {                                                      \
            const int kg = ((KT) + 2) * 32 + khalf * 16;                            \
            const float* seg = (kg < 1024) ? A0 : (kg < 2048) ? A1                  \
                               : (kg < 3072) ? A2 : A3;                             \
            const float4* ap = (const float4*)(seg + aRowOff + (kg & 1023));        \
            NXT[0] = ap[0]; NXT[1] = ap[1]; NXT[2] = ap[2]; NXT[3] = ap[3];         \
        }                                                                           \
        if ((KT) + 1 < KT_N) {                                                      \
            char* lB = bufn + 32768;                                                \
            const char* s0 = gB0 + (((size_t)((KT) + 1)) << 14);                    \
            const char* s1 = gB1 + (((size_t)((KT) + 1)) << 14);                    \
            gload16(s0 + t * 16,        lB + t * 16);                               \
            gload16(s0 + 8192 + t * 16, lB + 8192 + t * 16);                        \
            gload16(s1 + t * 16,        lB + 16384 + t * 16);                       \
            gload16(s1 + 8192 + t * 16, lB + 24576 + t * 16);                       \
            int4 h0, l0, h1, l1;                                                    \
            split8(CUR[0], CUR[1], h0, l0);                                         \
            split8(CUR[2], CUR[3], h1, l1);                                         \
            *(int4*)(bufn + wA0)        = h0;                                       \
            *(int4*)(bufn + (wA0 ^ 64)) = l0;                                       \
            *(int4*)(bufn + wA1)        = h1;                                       \
            *(int4*)(bufn + (wA1 ^ 64)) = l1;                                       \
        }                                                                           \
        short8 bh[4], bl[4];                                                        \
        _Pragma("unroll")                                                           \
        for (int nf = 0; nf < 4; ++nf) {                                            \
            bh[nf] = *(const short8*)(bufcB + (bBase + nf * 2048));                 \
            bl[nf] = *(const short8*)(bufcB + ((bBase + nf * 2048) ^ 64));          \
        }                                                                           \
        if (stag == 0) { PHASE(0) PHASE(1) PHASE(2) PHASE(3) }                      \
        else           { PHASE(2) PHASE(3) PHASE(0) PHASE(1) }                      \
        __syncthreads();                                                            \
    }

__global__ __launch_bounds__(512, 1) void gemm1_mfma_kernel(
    const float* __restrict__ A0, const float* __restrict__ A1,
    const float* __restrict__ A2, const float* __restrict__ A3,
    const char* __restrict__ Wp, const float* __restrict__ b1,
    float* __restrict__ hidden)
{
    extern __shared__ __align__(16) char smem[];   // 131072

    // B-locality mapping: each XCD (bid&7) serves ONE nt -> B L2-resident.
    // nt = (bid&7)&3 ; mt = (bid>>3) + 32*((bid&7)>>2). Bijective over 64x4.
    const int xcd = blockIdx.x & 7;
    const int nt  = xcd & 3;
    const int mt  = (blockIdx.x >> 3) + ((xcd >> 2) << 5);

    const int t    = threadIdx.x;
    const int lane = t & 63;
    const int wid  = t >> 6;                 // 0..7
    const int wr = wid >> 2, wc = wid & 3;   // 2 x 4 waves, wave tile 128x64
    const int lrow = lane & 15;
    const int lk   = lane >> 4;

    // stagger bit: differs between SIMD-sharing waves under either wave mapping
    const int stag = (wid ^ (wid >> 2)) & 1;

    const int rowL  = t >> 1;
    const int khalf = t & 1;
    const size_t aRowOff = (size_t)(mt * 256 + rowL) * HD;

    const char* gB0 = Wp + (((size_t)((nt * 2)     * KT_N)) << 14);
    const char* gB1 = Wp + (((size_t)((nt * 2 + 1) * KT_N)) << 14);

    const unsigned aBase = (unsigned)(wr * 128 + lrow) * 128
                         + (((unsigned)lk ^ (unsigned)(lrow & 7)) << 4);
    const unsigned bBase = (unsigned)(wc >> 1) * 16384
                         + (unsigned)((wc & 1) * 64 + lrow) * 128
                         + (((unsigned)lk ^ (unsigned)(lrow & 7)) << 4);

    const int r7 = rowL & 7;
    const unsigned wA0 = (unsigned)rowL * 128 + (((unsigned)(2 * khalf)     ^ (unsigned)r7) << 4);
    const unsigned wA1 = (unsigned)rowL * 128 + (((unsigned)(2 * khalf + 1) ^ (unsigned)r7) << 4);

    f32x4 acc[8][4];
#pragma unroll
    for (int i = 0; i < 8; ++i)
#pragma unroll
        for (int j = 0; j < 4; ++j) acc[i][j] = (f32x4){0.f, 0.f, 0.f, 0.f};

    float4 rA0[4], rA1[4];

    // ---- prologue ----
    {
        // A(0): load, split, write buf0 (compiler inserts the waitcnt)
        const float4* ap = (const float4*)(A0 + aRowOff + khalf * 16);
        const float4 f0 = ap[0], f1 = ap[1], f2 = ap[2], f3 = ap[3];
        int4 h0, l0, h1, l1;
        split8(f0, f1, h0, l0);
        split8(f2, f3, h1, l1);
        *(int4*)(smem + wA0)        = h0;
        *(int4*)(smem + (wA0 ^ 64)) = l0;
        *(int4*)(smem + wA1)        = h1;
        *(int4*)(smem + (wA1 ^ 64)) = l1;
        // A(1) -> rA0 (kg = 32 + khalf*16 < 1024 -> segment A0)
        const float4* ap1 = (const float4*)(A0 + aRowOff + 32 + khalf * 16);
        rA0[0] = ap1[0]; rA0[1] = ap1[1]; rA0[2] = ap1[2]; rA0[3] = ap1[3];
        // B(0) gloads into buf0
        char* lB = smem + 32768;
        gload16(gB0 + t * 16,        lB + t * 16);
        gload16(gB0 + 8192 + t * 16, lB + 8192 + t * 16);
        gload16(gB1 + t * 16,        lB + 16384 + t * 16);
        gload16(gB1 + 8192 + t * 16, lB + 24576 + t * 16);
    }
    __syncthreads();   // drains vmcnt+lgkmcnt: buf0 complete, rA0 landed

    for (int kt2 = 0; kt2 < KT_N; kt2 += 2) {
        STEP(kt2,     rA0, rA1)
        STEP(kt2 + 1, rA1, rA0)
    }

    // ---- epilogue: bias + tanh (D: col = lane&15, row = lk*4 + r) ----
#pragma unroll
    for (int nf = 0; nf < 4; ++nf) {
        const int col = nt * 256 + wc * 64 + nf * 16 + lrow;
        const float bias = b1[col];
#pragma unroll
        for (int mf = 0; mf < 8; ++mf) {
            const int row0 = mt * 256 + wr * 128 + mf * 16 + lk * 4;
#pragma unroll
            for (int r = 0; r < 4; ++r)
                hidden[(size_t)(row0 + r) * HD + col] = tanhf(acc[mf][nf][r] + bias);
        }
    }
}

// ---------------- shared head/refine epilogue ----------------
__device__ __forceinline__ void finish_row(
    const float* __restrict__ acc, const float* __restrict__ b2,
    const void* __restrict__ mask, const int* __restrict__ real_actions,
    int fmt, int row, float* __restrict__ out,
    int* __restrict__ flagCnt, int* __restrict__ flagList, int lane)
{
    float masked[NACT];
#pragma unroll
    for (int a = 0; a < NACT; ++a) {
        const float lg = acc[a] + b2[a];
        bool valid;
        if (fmt == 0)      valid = ((const unsigned char*)mask)[(size_t)row * NACT + a] != 0;
        else if (fmt == 1) valid = ((const int*)mask)[(size_t)row * NACT + a] != 0;
        else               valid = ((const float*)mask)[(size_t)row * NACT + a] != 0.f;
        masked[a] = valid ? lg : -1e9f;
    }
    float m = masked[0], m2 = -3e38f;
    int amax = 0;
#pragma unroll
    for (int a = 1; a < NACT; ++a) {
        const float v = masked[a];
        if (v > m) { m2 = m; m = v; amax = a; }
        else if (v > m2) m2 = v;
    }
    float s = 0.f;
#pragma unroll
    for (int a = 0; a < NACT; ++a) s += expf(masked[a] - m);
    const float lse = m + logf(s);
    const int ga = real_actions[row];
    float gl = masked[0];
#pragma unroll
    for (int a = 1; a < NACT; ++a) gl = (ga == a) ? masked[a] : gl;
    if (lane == 0) {
        out[row] = (float)amax;
        out[BTOT + row] = gl - lse;
        if (flagList != nullptr && (m - m2) < 1e-3f) {
            const int ix = atomicAdd(flagCnt, 1);
            flagList[ix] = row;
        }
    }
}

// ---------------- head: 2 rows per wave (W2 loads reused) ----------------
__global__ __launch_bounds__(256) void head_kernel(
    const float* __restrict__ hidden, const float* __restrict__ W2,
    const float* __restrict__ b2, const void* __restrict__ mask,
    const int* __restrict__ real_actions, int* __restrict__ ctr,
    int* __restrict__ flagList, float* __restrict__ out, int rowBase)
{
    const int lane = threadIdx.x & 63;
    const int lr0  = (blockIdx.x * 4 + (threadIdx.x >> 6)) * 2;

    float a0[NACT], a1[NACT];
#pragma unroll
    for (int a = 0; a < NACT; ++a) { a0[a] = 0.f; a1[a] = 0.f; }

    const float* h0 = hidden + (size_t)lr0 * HD;
    const float* h1 = h0 + HD;
#pragma unroll 4
    for (int j = 0; j < 16; ++j) {
        const int h = lane + 64 * j;
        const float hv0 = h0[h];
        const float hv1 = h1[h];
        const float4* w4 = (const float4*)(W2 + (size_t)h * NACT);
        const float4 w0 = w4[0], w1 = w4[1], w2 = w4[2], w3 = w4[3], w4v = w4[4];
        a0[0]  = fmaf(hv0, w0.x,  a0[0]);  a1[0]  = fmaf(hv1, w0.x,  a1[0]);
        a0[1]  = fmaf(hv0, w0.y,  a0[1]);  a1[1]  = fmaf(hv1, w0.y,  a1[1]);
        a0[2]  = fmaf(hv0, w0.z,  a0[2]);  a1[2]  = fmaf(hv1, w0.z,  a1[2]);
        a0[3]  = fmaf(hv0, w0.w,  a0[3]);  a1[3]  = fmaf(hv1, w0.w,  a1[3]);
        a0[4]  = fmaf(hv0, w1.x,  a0[4]);  a1[4]  = fmaf(hv1, w1.x,  a1[4]);
        a0[5]  = fmaf(hv0, w1.y,  a0[5]);  a1[5]  = fmaf(hv1, w1.y,  a1[5]);
        a0[6]  = fmaf(hv0, w1.z,  a0[6]);  a1[6]  = fmaf(hv1, w1.z,  a1[6]);
        a0[7]  = fmaf(hv0, w1.w,  a0[7]);  a1[7]  = fmaf(hv1, w1.w,  a1[7]);
        a0[8]  = fmaf(hv0, w2.x,  a0[8]);  a1[8]  = fmaf(hv1, w2.x,  a1[8]);
        a0[9]  = fmaf(hv0, w2.y,  a0[9]);  a1[9]  = fmaf(hv1, w2.y,  a1[9]);
        a0[10] = fmaf(hv0, w2.z,  a0[10]); a1[10] = fmaf(hv1, w2.z,  a1[10]);
        a0[11] = fmaf(hv0, w2.w,  a0[11]); a1[11] = fmaf(hv1, w2.w,  a1[11]);
        a0[12] = fmaf(hv0, w3.x,  a0[12]); a1[12] = fmaf(hv1, w3.x,  a1[12]);
        a0[13] = fmaf(hv0, w3.y,  a0[13]); a1[13] = fmaf(hv1, w3.y,  a1[13]);
        a0[14] = fmaf(hv0, w3.z,  a0[14]); a1[14] = fmaf(hv1, w3.z,  a1[14]);
        a0[15] = fmaf(hv0, w3.w,  a0[15]); a1[15] = fmaf(hv1, w3.w,  a1[15]);
        a0[16] = fmaf(hv0, w4v.x, a0[16]); a1[16] = fmaf(hv1, w4v.x, a1[16]);
        a0[17] = fmaf(hv0, w4v.y, a0[17]); a1[17] = fmaf(hv1, w4v.y, a1[17]);
        a0[18] = fmaf(hv0, w4v.z, a0[18]); a1[18] = fmaf(hv1, w4v.z, a1[18]);
        a0[19] = fmaf(hv0, w4v.w, a0[19]); a1[19] = fmaf(hv1, w4v.w, a1[19]);
    }
#pragma unroll
    for (int off = 32; off; off >>= 1) {
#pragma unroll
        for (int a = 0; a < NACT; ++a) {
            a0[a] += __shfl_xor(a0[a], off, 64);
            a1[a] += __shfl_xor(a1[a], off, 64);
        }
    }

    const int c1 = ctr[1], c2 = ctr[2], c3 = ctr[3];
    const int fmt = (c1 > 0) ? 0 : ((c2 > 0 || c3 > 0) ? 2 : 1);

    finish_row(a0, b2, mask, real_actions, fmt, rowBase + lr0,     out, &ctr[4], flagList, lane);
    finish_row(a1, b2, mask, real_actions, fmt, rowBase + lr0 + 1, out, &ctr[4], flagList, lane);
}

// ---------------- refine pass 1: exact f32 hidden rows (TLP version) ----------------
__global__ __launch_bounds__(256) void refine_hidden_kernel(
    const float* __restrict__ A0, const float* __restrict__ A1,
    const float* __restrict__ A2, const float* __restrict__ A3,
    const float* __restrict__ W1, const float* __restrict__ b1,
    const int* __restrict__ ctr, const int* __restrict__ list,
    float* __restrict__ hiddenR, int cap)
{
    __shared__ float xs[2][KTOT];
    __shared__ float red[2][4][64];
    const int tid = threadIdx.x;
    int count = ctr[4]; if (count > cap) count = cap;
    const int total = ((count + 1) >> 1) << 4;

    for (int u = blockIdx.x; u < total; u += gridDim.x) {
        const int p  = u >> 4;
        const int f0 = 2 * p;
        const int f1 = (2 * p + 1 < count) ? (2 * p + 1) : f0;
        const int r0 = list[f0];
        const int r1 = list[f1];
        const int colBase = (u & 15) << 6;

        for (int i = tid; i < KTOT; i += 256) {
            const float* seg = (i < 1024) ? A0 : (i < 2048) ? A1 : (i < 3072) ? A2 : A3;
            xs[0][i] = seg[(size_t)r0 * HD + (i & 1023)];
            xs[1][i] = seg[(size_t)r1 * HD + (i & 1023)];
        }
        __syncthreads();

        const int col   = colBase + (tid & 63);
        const int kbase = (tid >> 6) << 10;
        const float* Wc = W1 + col;
        float acc0 = 0.f, acc1 = 0.f;

        float wa[16], wb[16];
#pragma unroll
        for (int v = 0; v < 16; ++v) wa[v] = Wc[(size_t)(kbase + v) * HD];
#pragma unroll
        for (int v = 0; v < 16; ++v) wb[v] = Wc[(size_t)(kbase + 16 + v) * HD];

        const int kend = kbase + 1024;
        for (int k0 = kbase; k0 < kend; k0 += 32) {
#pragma unroll
            for (int v = 0; v < 16; ++v) {
                acc0 = fmaf(xs[0][k0 + v], wa[v], acc0);
                acc1 = fmaf(xs[1][k0 + v], wa[v], acc1);
            }
            if (k0 + 32 < kend) {
#pragma unroll
                for (int v = 0; v < 16; ++v)
                    wa[v] = Wc[(size_t)(k0 + 32 + v) * HD];
            }
#pragma unroll
            for (int v = 0; v < 16; ++v) {
                acc0 = fmaf(xs[0][k0 + 16 + v], wb[v], acc0);
                acc1 = fmaf(xs[1][k0 + 16 + v], wb[v], acc1);
            }
            if (k0 + 48 < kend) {
#pragma unroll
                for (int v = 0; v < 16; ++v)
                    wb[v] = Wc[(size_t)(k0 + 48 + v) * HD];
            }
        }

        red[0][tid >> 6][tid & 63] = acc0;
        red[1][tid >> 6][tid & 63] = acc1;
        __syncthreads();

        if (tid < 128) {
            const int r = tid >> 6, c = tid & 63;
            const float s = red[r][0][c] + red[r][1][c] + red[r][2][c] + red[r][3][c];
            const int f = r ? f1 : f0;
            hiddenR[(size_t)f * HD + colBase + c] = tanhf(s + b1[colBase + c]);
        }
        __syncthreads();
    }
}

// ---------------- refine pass 2: exact head for flagged rows ----------------
__global__ __launch_bounds__(256) void refine_head_kernel(
    const float* __restrict__ hiddenR, const float* __restrict__ W2,
    const float* __restrict__ b2, const void* __restrict__ mask,
    const int* __restrict__ real_actions, const int* __restrict__ ctr,
    const int* __restrict__ list, float* __restrict__ out, int cap)
{
    const int lane = threadIdx.x & 63;
    const int wv   = threadIdx.x >> 6;
    int count = ctr[4]; if (count > cap) count = cap;
    const int c1 = ctr[1], c2 = ctr[2], c3 = ctr[3];
    const int fmt = (c1 > 0) ? 0 : ((c2 > 0 || c3 > 0) ? 2 : 1);

    for (int f = blockIdx.x * 4 + wv; f < count; f += gridDim.x * 4) {
        const int row = list[f];
        const float* hrow = hiddenR + (size_t)f * HD;
        float a20[NACT];
#pragma unroll
        for (int a = 0; a < NACT; ++a) a20[a] = 0.f;
#pragma unroll 4
        for (int m = 0; m < 16; ++m) {
            const int h = lane + 64 * m;
            const float hv = hrow[h];
            const float4* w4 = (const float4*)(W2 + (size_t)h * NACT);
            const float4 w0 = w4[0], w1 = w4[1], w2 = w4[2], w3 = w4[3], w4v = w4[4];
            a20[0]  = fmaf(hv, w0.x,  a20[0]);  a20[1]  = fmaf(hv, w0.y,  a20[1]);
            a20[2]  = fmaf(hv, w0.z,  a20[2]);  a20[3]  = fmaf(hv, w0.w,  a20[3]);
            a20[4]  = fmaf(hv, w1.x,  a20[4]);  a20[5]  = fmaf(hv, w1.y,  a20[5]);
            a20[6]  = fmaf(hv, w1.z,  a20[6]);  a20[7]  = fmaf(hv, w1.w,  a20[7]);
            a20[8]  = fmaf(hv, w2.x,  a20[8]);  a20[9]  = fmaf(hv, w2.y,  a20[9]);
            a20[10] = fmaf(hv, w2.z,  a20[10]); a20[11] = fmaf(hv, w2.w,  a20[11]);
            a20[12] = fmaf(hv, w3.x,  a20[12]); a20[13] = fmaf(hv, w3.y,  a20[13]);
            a20[14] = fmaf(hv, w3.z,  a20[14]); a20[15] = fmaf(hv, w3.w,  a20[15]);
            a20[16] = fmaf(hv, w4v.x, a20[16]); a20[17] = fmaf(hv, w4v.y, a20[17]);
            a20[18] = fmaf(hv, w4v.z, a20[18]); a20[19] = fmaf(hv, w4v.w, a20[19]);
        }
#pragma unroll
        for (int off = 32; off; off >>= 1) {
#pragma unroll
            for (int a = 0; a < NACT; ++a) a20[a] += __shfl_xor(a20[a], off, 64);
        }
        finish_row(a20, b2, mask, real_actions, fmt, row, out, nullptr, nullptr, lane);
    }
}

// ---------------- launcher ----------------
extern "C" void kernel_launch(void* const* d_in, const int* in_sizes, int n_in,
                              void* d_out, int out_size, void* d_ws, size_t ws_size,
                              hipStream_t stream)
{
    const float* buf_h = (const float*)d_in[0];
    const float* stk_h = (const float*)d_in[1];
    const float* out_h = (const float*)d_in[2];
    const float* act_h = (const float*)d_in[3];
    const float* W1    = (const float*)d_in[4];
    const float* b1    = (const float*)d_in[5];
    const float* W2    = (const float*)d_in[6];
    const float* b2    = (const float*)d_in[7];
    const void*  mask  = d_in[8];
    const int*   ra    = (const int*)d_in[9];
    float*       out   = (float*)d_out;

    int*  ctr      = (int*)d_ws;
    int*  flagList = (int*)((char*)d_ws + 256);
    char* Wp       = (char*)d_ws + 256 + 65536;
    const size_t wpBytes = (size_t)8 * KT_N * 16384;           // 16 MiB
    float* hidden  = (float*)(Wp + wpBytes);

    hipMemsetAsync(d_ws, 0, 256, stream);
    detect_mask_kernel<<<64, 256, 0, stream>>>(
        (const unsigned int*)mask, BTOT * NACT / 4, ctr);
    wpack_kernel<<<8 * KT_N, 256, 0, stream>>>(W1, Wp);

    hipFuncSetAttribute((const void*)gemm1_mfma_kernel,
                        hipFuncAttributeMaxDynamicSharedMemorySize, 131072);

    gemm1_mfma_kernel<<<256, 512, 131072, stream>>>(
        buf_h, stk_h, out_h, act_h, Wp, b1, hidden);
    head_kernel<<<BTOT / 8, 256, 0, stream>>>(
        hidden, W2, b2, mask, ra, ctr, flagList, out, 0);

    float* hiddenR = hidden;
    refine_hidden_kernel<<<2048, 256, 0, stream>>>(
        buf_h, stk_h, out_h, act_h, W1, b1, ctr, flagList, hiddenR, BTOT);
    refine_head_kernel<<<64, 256, 0, stream>>>(
        hiddenR, W2, b2, mask, ra, ctr, flagList, out, BTOT);
}

// Round 14
// 510.779 us; speedup vs baseline: 3.7612x; 3.7612x over previous
//
#include <hip/hip_runtime.h>
#include <math.h>

// TransitionNER head:  hidden = tanh(concat(4x[B,1024]) @ W1 + b1)
//                      logits = hidden @ W2 + b2 ; masked log-softmax ; argmax + gold gather
// B=16384, H=1024, A=20, K=4096.
//
// Round 14: revert r13 entirely (depth-2 reg pipeline spilled: 6GB scratch traffic;
// B-remap solved a non-problem). Base = r11 skeleton (best: 451us gemm, absmax 0).
// Change: 2-pass numerics. A = single RNE bf16, B = hi/lo split:
//   C = A_bf16*(Bh+Bl); error = al*W1 -> logit RMS ~2.6e-4 (5sigma=1.3e-3).
//   refine flag gap widened 1e-3 -> 4e-3 (~15sigma; ~300 rows refined exactly).
// Per step: MFMA 96->64/wave, LDS frag reads 24->16, A split VALU & ds_writes halved.
// head/refine/wpack/detect unchanged.

#define BTOT 16384
#define HD   1024
#define NACT 20
#define KTOT 4096
#define KT_N 128          // number of 32-wide k tiles

typedef __attribute__((ext_vector_type(8))) short short8;
typedef __attribute__((ext_vector_type(4))) float f32x4;

#define MFMA(a, b, c) __builtin_amdgcn_mfma_f32_16x16x32_bf16((a), (b), (c), 0, 0, 0)

// ---------------- global -> LDS direct load (16B) ----------------
__device__ __forceinline__ void gload16(const void* g, void* l)
{
    auto gp = (const __attribute__((address_space(1))) unsigned int*)((uintptr_t)g);
    auto lp = (__attribute__((address_space(3))) unsigned int*)((uintptr_t)l);
    __builtin_amdgcn_global_load_lds(gp, lp, 16, 0, 0);
}

// ---------------- bf16 helpers (RNE) ----------------
// full hi/lo split (used by wpack for B)
__device__ __forceinline__ void split8(const float4 v0, const float4 v1,
                                       int4& hi, int4& lo)
{
    const float f[8] = {v0.x, v0.y, v0.z, v0.w, v1.x, v1.y, v1.z, v1.w};
    unsigned hp[4], lp[4];
#pragma unroll
    for (int i = 0; i < 4; ++i) {
        const unsigned u0 = __float_as_uint(f[2 * i]);
        const unsigned u1 = __float_as_uint(f[2 * i + 1]);
        const unsigned r0 = u0 + 0x7FFFu + ((u0 >> 16) & 1u);
        const unsigned r1 = u1 + 0x7FFFu + ((u1 >> 16) & 1u);
        hp[i] = (r0 >> 16) | (r1 & 0xFFFF0000u);
        const float h0 = __uint_as_float(r0 & 0xFFFF0000u);
        const float h1 = __uint_as_float(r1 & 0xFFFF0000u);
        const float d0 = f[2 * i] - h0;
        const float d1 = f[2 * i + 1] - h1;
        const unsigned s0 = __float_as_uint(d0);
        const unsigned s1 = __float_as_uint(d1);
        const unsigned q0 = s0 + 0x7FFFu + ((s0 >> 16) & 1u);
        const unsigned q1 = s1 + 0x7FFFu + ((s1 >> 16) & 1u);
        lp[i] = (q0 >> 16) | (q1 & 0xFFFF0000u);
    }
    hi = make_int4((int)hp[0], (int)hp[1], (int)hp[2], (int)hp[3]);
    lo = make_int4((int)lp[0], (int)lp[1], (int)lp[2], (int)lp[3]);
}

// hi-only RNE convert (used by gemm A staging)
__device__ __forceinline__ int4 cvt8(const float4 v0, const float4 v1)
{
    const float f[8] = {v0.x, v0.y, v0.z, v0.w, v1.x, v1.y, v1.z, v1.w};
    unsigned hp[4];
#pragma unroll
    for (int i = 0; i < 4; ++i) {
        const unsigned u0 = __float_as_uint(f[2 * i]);
        const unsigned u1 = __float_as_uint(f[2 * i + 1]);
        const unsigned r0 = u0 + 0x7FFFu + ((u0 >> 16) & 1u);
        const unsigned r1 = u1 + 0x7FFFu + ((u1 >> 16) & 1u);
        hp[i] = (r0 >> 16) | (r1 & 0xFFFF0000u);
    }
    return make_int4((int)hp[0], (int)hp[1], (int)hp[2], (int)hp[3]);
}

// ---------------- mask dtype detection ----------------
__global__ __launch_bounds__(256) void detect_mask_kernel(
    const unsigned int* __restrict__ w, int nwords, int* __restrict__ ctr)
{
    int c0 = 0, c1 = 0, c2 = 0, c3 = 0;
    for (int i = blockIdx.x * 256 + threadIdx.x; i < nwords; i += gridDim.x * 256) {
        unsigned int v = w[i];
        c0 += (v & 0x000000FFu) ? 1 : 0;
        c1 += (v & 0x0000FF00u) ? 1 : 0;
        c2 += (v & 0x00FF0000u) ? 1 : 0;
        c3 += (v & 0xFF000000u) ? 1 : 0;
    }
#pragma unroll
    for (int off = 32; off; off >>= 1) {
        c0 += __shfl_xor(c0, off, 64);
        c1 += __shfl_xor(c1, off, 64);
        c2 += __shfl_xor(c2, off, 64);
        c3 += __shfl_xor(c3, off, 64);
    }
    if ((threadIdx.x & 63) == 0) {
        atomicAdd(&ctr[0], c0);
        atomicAdd(&ctr[1], c1);
        atomicAdd(&ctr[2], c2);
        atomicAdd(&ctr[3], c3);
    }
}

// ---------------- W pack: [K][N] f32 -> swizzled bf16 hi/lo tile images ----------------
__global__ __launch_bounds__(256) void wpack_kernel(
    const float* __restrict__ W1, char* __restrict__ Wp)
{
    const int b  = blockIdx.x;
    const int t  = threadIdx.x;
    const int nt = b >> 7;
    const int kt = b & 127;
    const int nn = t & 127;
    const int h  = t >> 7;

    float f[16];
#pragma unroll
    for (int kk = 0; kk < 16; ++kk)
        f[kk] = W1[(size_t)(kt * 32 + h * 16 + kk) * HD + nt * 128 + nn];

    int4 hi0, lo0, hi1, lo1;
    split8(make_float4(f[0], f[1], f[2], f[3]),
           make_float4(f[4], f[5], f[6], f[7]), hi0, lo0);
    split8(make_float4(f[8], f[9], f[10], f[11]),
           make_float4(f[12], f[13], f[14], f[15]), hi1, lo1);

    char* rowp = Wp + (((size_t)(nt * KT_N + kt)) << 14) + nn * 128;
    const int r7 = nn & 7;
    const int s0 = ((2 * h) ^ r7) << 4;
    const int s1 = ((2 * h + 1) ^ r7) << 4;
    *(int4*)(rowp + s0)        = hi0;
    *(int4*)(rowp + s1)        = hi1;
    *(int4*)(rowp + (s0 ^ 64)) = lo0;
    *(int4*)(rowp + (s1 ^ 64)) = lo1;
}

// ---------------- GEMM1: 256x256 tile, 8 waves, staggered 2-pass MFMA ----------------
// grid = 256 blocks (1/CU). LDS 128KB dynamic: [buf][A 32K | B 32K].
// A = single bf16 (slots 0-3 of each 128B row; slots 4-7 unused).

// One phase = one A-fragment pair x all 4 B-frags, 2-pass (bh then bl per acc).
#define PHASE(AP)                                                                   \
    {                                                                               \
        const short8 ah0 = *(const short8*)(bufc + (aBase + (2*(AP)) * 2048));      \
        const short8 ah1 = *(const short8*)(bufc + (aBase + (2*(AP)+1) * 2048));    \
        __builtin_amdgcn_s_setprio(1);                                              \
        _Pragma("unroll")                                                           \
        for (int nf = 0; nf < 4; ++nf) {                                            \
            acc[2*(AP)][nf]   = MFMA(ah0, bh[nf], acc[2*(AP)][nf]);                 \
            acc[2*(AP)][nf]   = MFMA(ah0, bl[nf], acc[2*(AP)][nf]);                 \
            acc[2*(AP)+1][nf] = MFMA(ah1, bh[nf], acc[2*(AP)+1][nf]);               \
            acc[2*(AP)+1][nf] = MFMA(ah1, bl[nf], acc[2*(AP)+1][nf]);               \
        }                                                                           \
        __builtin_amdgcn_s_setprio(0);                                              \
    }

__global__ __launch_bounds__(512, 1) void gemm1_mfma_kernel(
    const float* __restrict__ A0, const float* __restrict__ A1,
    const float* __restrict__ A2, const float* __restrict__ A3,
    const char* __restrict__ Wp, const float* __restrict__ b1,
    float* __restrict__ hidden)
{
    extern __shared__ __align__(16) char smem[];   // 131072

    // XCD-chunked bijective swizzle (nwg = 256, %8 == 0) — r11 mapping
    const int newbid = (blockIdx.x & 7) * 32 + (blockIdx.x >> 3);
    const int mt = newbid >> 2;
    const int nt = newbid & 3;

    const int t    = threadIdx.x;
    const int lane = t & 63;
    const int wid  = t >> 6;                 // 0..7
    const int wr = wid >> 2, wc = wid & 3;   // 2 x 4 waves, wave tile 128x64
    const int lrow = lane & 15;
    const int lk   = lane >> 4;

    // stagger bit: differs between SIMD-sharing waves under either wave mapping
    const int stag = (wid ^ (wid >> 2)) & 1;

    const int rowL  = t >> 1;
    const int khalf = t & 1;
    const size_t aRowOff = (size_t)(mt * 256 + rowL) * HD;

    const char* gB0 = Wp + (((size_t)((nt * 2)     * KT_N)) << 14);
    const char* gB1 = Wp + (((size_t)((nt * 2 + 1) * KT_N)) << 14);

    const unsigned aBase = (unsigned)(wr * 128 + lrow) * 128
                         + (((unsigned)lk ^ (unsigned)(lrow & 7)) << 4);
    const unsigned bBase = (unsigned)(wc >> 1) * 16384
                         + (unsigned)((wc & 1) * 64 + lrow) * 128
                         + (((unsigned)lk ^ (unsigned)(lrow & 7)) << 4);

    const int r7 = rowL & 7;
    const unsigned wA0 = (unsigned)rowL * 128 + (((unsigned)(2 * khalf)     ^ (unsigned)r7) << 4);
    const unsigned wA1 = (unsigned)rowL * 128 + (((unsigned)(2 * khalf + 1) ^ (unsigned)r7) << 4);

    f32x4 acc[8][4];
#pragma unroll
    for (int i = 0; i < 8; ++i)
#pragma unroll
        for (int j = 0; j < 4; ++j) acc[i][j] = (f32x4){0.f, 0.f, 0.f, 0.f};

    // ---- prologue: stage kt = 0 into buf 0 ----
    {
        const float4* ap = (const float4*)(A0 + aRowOff + khalf * 16);
        const float4 f0 = ap[0], f1 = ap[1], f2 = ap[2], f3 = ap[3];
        const int4 h0 = cvt8(f0, f1);
        const int4 h1 = cvt8(f2, f3);
        char* lA = smem;
        *(int4*)(lA + wA0) = h0;
        *(int4*)(lA + wA1) = h1;
        char* lB = smem + 32768;
        gload16(gB0 + t * 16,        lB + t * 16);
        gload16(gB0 + 8192 + t * 16, lB + 8192 + t * 16);
        gload16(gB1 + t * 16,        lB + 16384 + t * 16);
        gload16(gB1 + 8192 + t * 16, lB + 24576 + t * 16);
    }
    __syncthreads();

    for (int kt = 0; kt < KT_N; ++kt) {
        const int cur = kt & 1;
        const char* bufc  = smem + cur * 65536;
        const char* bufcB = bufc + 32768;
        char*       bufn  = smem + (cur ^ 1) * 65536;
        const bool pref = (kt + 1 < KT_N);

        float4 f0, f1, f2, f3;
        if (pref) {
            // issue B gload_lds into bufn (in flight across the MFMAs)
            char* lB = bufn + 32768;
            const char* s0 = gB0 + (((size_t)(kt + 1)) << 14);
            const char* s1 = gB1 + (((size_t)(kt + 1)) << 14);
            gload16(s0 + t * 16,        lB + t * 16);
            gload16(s0 + 8192 + t * 16, lB + 8192 + t * 16);
            gload16(s1 + t * 16,        lB + 16384 + t * 16);
            gload16(s1 + 8192 + t * 16, lB + 24576 + t * 16);
            // issue A f32 loads -> regs (consumed after the MFMAs)
            const int kg = (kt + 1) * 32 + khalf * 16;
            const float* seg = (kg < 1024) ? A0 : (kg < 2048) ? A1 : (kg < 3072) ? A2 : A3;
            const float4* ap = (const float4*)(seg + aRowOff + (kg & 1023));
            f0 = ap[0]; f1 = ap[1]; f2 = ap[2]; f3 = ap[3];
        }

        // B fragments: read once, held across all phases
        short8 bh[4], bl[4];
#pragma unroll
        for (int nf = 0; nf < 4; ++nf) {
            bh[nf] = *(const short8*)(bufcB + (bBase + nf * 2048));
            bl[nf] = *(const short8*)(bufcB + ((bBase + nf * 2048) ^ 64));
        }

        // staggered phase walk: SIMD-sharing waves half a step apart
        if (stag == 0) {
            PHASE(0) PHASE(1) PHASE(2) PHASE(3)
        } else {
            PHASE(2) PHASE(3) PHASE(0) PHASE(1)
        }

        if (pref) {
            const int4 h0 = cvt8(f0, f1);
            const int4 h1 = cvt8(f2, f3);
            *(int4*)(bufn + wA0) = h0;
            *(int4*)(bufn + wA1) = h1;
        }
        __syncthreads();
    }

    // ---- epilogue: bias + tanh (D: col = lane&15, row = lk*4 + r) ----
#pragma unroll
    for (int nf = 0; nf < 4; ++nf) {
        const int col = nt * 256 + wc * 64 + nf * 16 + lrow;
        const float bias = b1[col];
#pragma unroll
        for (int mf = 0; mf < 8; ++mf) {
            const int row0 = mt * 256 + wr * 128 + mf * 16 + lk * 4;
#pragma unroll
            for (int r = 0; r < 4; ++r)
                hidden[(size_t)(row0 + r) * HD + col] = tanhf(acc[mf][nf][r] + bias);
        }
    }
}

// ---------------- shared head/refine epilogue ----------------
__device__ __forceinline__ void finish_row(
    const float* __restrict__ acc, const float* __restrict__ b2,
    const void* __restrict__ mask, const int* __restrict__ real_actions,
    int fmt, int row, float* __restrict__ out,
    int* __restrict__ flagCnt, int* __restrict__ flagList, int lane)
{
    float masked[NACT];
#pragma unroll
    for (int a = 0; a < NACT; ++a) {
        const float lg = acc[a] + b2[a];
        bool valid;
        if (fmt == 0)      valid = ((const unsigned char*)mask)[(size_t)row * NACT + a] != 0;
        else if (fmt == 1) valid = ((const int*)mask)[(size_t)row * NACT + a] != 0;
        else               valid = ((const float*)mask)[(size_t)row * NACT + a] != 0.f;
        masked[a] = valid ? lg : -1e9f;
    }
    float m = masked[0], m2 = -3e38f;
    int amax = 0;
#pragma unroll
    for (int a = 1; a < NACT; ++a) {
        const float v = masked[a];
        if (v > m) { m2 = m; m = v; amax = a; }
        else if (v > m2) m2 = v;
    }
    float s = 0.f;
#pragma unroll
    for (int a = 0; a < NACT; ++a) s += expf(masked[a] - m);
    const float lse = m + logf(s);
    const int ga = real_actions[row];
    float gl = masked[0];
#pragma unroll
    for (int a = 1; a < NACT; ++a) gl = (ga == a) ? masked[a] : gl;
    if (lane == 0) {
        out[row] = (float)amax;
        out[BTOT + row] = gl - lse;
        // 2-pass gemm: logit err RMS ~2.6e-4 -> 4e-3 gap = ~15 sigma
        if (flagList != nullptr && (m - m2) < 4e-3f) {
            const int ix = atomicAdd(flagCnt, 1);
            flagList[ix] = row;
        }
    }
}

// ---------------- head: 2 rows per wave (W2 loads reused) ----------------
__global__ __launch_bounds__(256) void head_kernel(
    const float* __restrict__ hidden, const float* __restrict__ W2,
    const float* __restrict__ b2, const void* __restrict__ mask,
    const int* __restrict__ real_actions, int* __restrict__ ctr,
    int* __restrict__ flagList, float* __restrict__ out, int rowBase)
{
    const int lane = threadIdx.x & 63;
    const int lr0  = (blockIdx.x * 4 + (threadIdx.x >> 6)) * 2;

    float a0[NACT], a1[NACT];
#pragma unroll
    for (int a = 0; a < NACT; ++a) { a0[a] = 0.f; a1[a] = 0.f; }

    const float* h0 = hidden + (size_t)lr0 * HD;
    const float* h1 = h0 + HD;
#pragma unroll 4
    for (int j = 0; j < 16; ++j) {
        const int h = lane + 64 * j;
        const float hv0 = h0[h];
        const float hv1 = h1[h];
        const float4* w4 = (const float4*)(W2 + (size_t)h * NACT);
        const float4 w0 = w4[0], w1 = w4[1], w2 = w4[2], w3 = w4[3], w4v = w4[4];
        a0[0]  = fmaf(hv0, w0.x,  a0[0]);  a1[0]  = fmaf(hv1, w0.x,  a1[0]);
        a0[1]  = fmaf(hv0, w0.y,  a0[1]);  a1[1]  = fmaf(hv1, w0.y,  a1[1]);
        a0[2]  = fmaf(hv0, w0.z,  a0[2]);  a1[2]  = fmaf(hv1, w0.z,  a1[2]);
        a0[3]  = fmaf(hv0, w0.w,  a0[3]);  a1[3]  = fmaf(hv1, w0.w,  a1[3]);
        a0[4]  = fmaf(hv0, w1.x,  a0[4]);  a1[4]  = fmaf(hv1, w1.x,  a1[4]);
        a0[5]  = fmaf(hv0, w1.y,  a0[5]);  a1[5]  = fmaf(hv1, w1.y,  a1[5]);
        a0[6]  = fmaf(hv0, w1.z,  a0[6]);  a1[6]  = fmaf(hv1, w1.z,  a1[6]);
        a0[7]  = fmaf(hv0, w1.w,  a0[7]);  a1[7]  = fmaf(hv1, w1.w,  a1[7]);
        a0[8]  = fmaf(hv0, w2.x,  a0[8]);  a1[8]  = fmaf(hv1, w2.x,  a1[8]);
        a0[9]  = fmaf(hv0, w2.y,  a0[9]);  a1[9]  = fmaf(hv1, w2.y,  a1[9]);
        a0[10] = fmaf(hv0, w2.z,  a0[10]); a1[10] = fmaf(hv1, w2.z,  a1[10]);
        a0[11] = fmaf(hv0, w2.w,  a0[11]); a1[11] = fmaf(hv1, w2.w,  a1[11]);
        a0[12] = fmaf(hv0, w3.x,  a0[12]); a1[12] = fmaf(hv1, w3.x,  a1[12]);
        a0[13] = fmaf(hv0, w3.y,  a0[13]); a1[13] = fmaf(hv1, w3.y,  a1[13]);
        a0[14] = fmaf(hv0, w3.z,  a0[14]); a1[14] = fmaf(hv1, w3.z,  a1[14]);
        a0[15] = fmaf(hv0, w3.w,  a0[15]); a1[15] = fmaf(hv1, w3.w,  a1[15]);
        a0[16] = fmaf(hv0, w4v.x, a0[16]); a1[16] = fmaf(hv1, w4v.x, a1[16]);
        a0[17] = fmaf(hv0, w4v.y, a0[17]); a1[17] = fmaf(hv1, w4v.y, a1[17]);
        a0[18] = fmaf(hv0, w4v.z, a0[18]); a1[18] = fmaf(hv1, w4v.z, a1[18]);
        a0[19] = fmaf(hv0, w4v.w, a0[19]); a1[19] = fmaf(hv1, w4v.w, a1[19]);
    }
#pragma unroll
    for (int off = 32; off; off >>= 1) {
#pragma unroll
        for (int a = 0; a < NACT; ++a) {
            a0[a] += __shfl_xor(a0[a], off, 64);
            a1[a] += __shfl_xor(a1[a], off, 64);
        }
    }

    const int c1 = ctr[1], c2 = ctr[2], c3 = ctr[3];
    const int fmt = (c1 > 0) ? 0 : ((c2 > 0 || c3 > 0) ? 2 : 1);

    finish_row(a0, b2, mask, real_actions, fmt, rowBase + lr0,     out, &ctr[4], flagList, lane);
    finish_row(a1, b2, mask, real_actions, fmt, rowBase + lr0 + 1, out, &ctr[4], flagList, lane);
}

// ---------------- refine pass 1: exact f32 hidden rows (TLP version) ----------------
__global__ __launch_bounds__(256) void refine_hidden_kernel(
    const float* __restrict__ A0, const float* __restrict__ A1,
    const float* __restrict__ A2, const float* __restrict__ A3,
    const float* __restrict__ W1, const float* __restrict__ b1,
    const int* __restrict__ ctr, const int* __restrict__ list,
    float* __restrict__ hiddenR, int cap)
{
    __shared__ float xs[2][KTOT];
    __shared__ float red[2][4][64];
    const int tid = threadIdx.x;
    int count = ctr[4]; if (count > cap) count = cap;
    const int total = ((count + 1) >> 1) << 4;

    for (int u = blockIdx.x; u < total; u += gridDim.x) {
        const int p  = u >> 4;
        const int f0 = 2 * p;
        const int f1 = (2 * p + 1 < count) ? (2 * p + 1) : f0;
        const int r0 = list[f0];
        const int r1 = list[f1];
        const int colBase = (u & 15) << 6;

        for (int i = tid; i < KTOT; i += 256) {
            const float* seg = (i < 1024) ? A0 : (i < 2048) ? A1 : (i < 3072) ? A2 : A3;
            xs[0][i] = seg[(size_t)r0 * HD + (i & 1023)];
            xs[1][i] = seg[(size_t)r1 * HD + (i & 1023)];
        }
        __syncthreads();

        const int col   = colBase + (tid & 63);
        const int kbase = (tid >> 6) << 10;
        const float* Wc = W1 + col;
        float acc0 = 0.f, acc1 = 0.f;

        float wa[16], wb[16];
#pragma unroll
        for (int v = 0; v < 16; ++v) wa[v] = Wc[(size_t)(kbase + v) * HD];
#pragma unroll
        for (int v = 0; v < 16; ++v) wb[v] = Wc[(size_t)(kbase + 16 + v) * HD];

        const int kend = kbase + 1024;
        for (int k0 = kbase; k0 < kend; k0 += 32) {
#pragma unroll
            for (int v = 0; v < 16; ++v) {
                acc0 = fmaf(xs[0][k0 + v], wa[v], acc0);
                acc1 = fmaf(xs[1][k0 + v], wa[v], acc1);
            }
            if (k0 + 32 < kend) {
#pragma unroll
                for (int v = 0; v < 16; ++v)
                    wa[v] = Wc[(size_t)(k0 + 32 + v) * HD];
            }
#pragma unroll
            for (int v = 0; v < 16; ++v) {
                acc0 = fmaf(xs[0][k0 + 16 + v], wb[v], acc0);
                acc1 = fmaf(xs[1][k0 + 16 + v], wb[v], acc1);
            }
            if (k0 + 48 < kend) {
#pragma unroll
                for (int v = 0; v < 16; ++v)
                    wb[v] = Wc[(size_t)(k0 + 48 + v) * HD];
            }
        }

        red[0][tid >> 6][tid & 63] = acc0;
        red[1][tid >> 6][tid & 63] = acc1;
        __syncthreads();

        if (tid < 128) {
            const int r = tid >> 6, c = tid & 63;
            const float s = red[r][0][c] + red[r][1][c] + red[r][2][c] + red[r][3][c];
            const int f = r ? f1 : f0;
            hiddenR[(size_t)f * HD + colBase + c] = tanhf(s + b1[colBase + c]);
        }
        __syncthreads();
    }
}

// ---------------- refine pass 2: exact head for flagged rows ----------------
__global__ __launch_bounds__(256) void refine_head_kernel(
    const float* __restrict__ hiddenR, const float* __restrict__ W2,
    const float* __restrict__ b2, const void* __restrict__ mask,
    const int* __restrict__ real_actions, const int* __restrict__ ctr,
    const int* __restrict__ list, float* __restrict__ out, int cap)
{
    const int lane = threadIdx.x & 63;
    const int wv   = threadIdx.x >> 6;
    int count = ctr[4]; if (count > cap) count = cap;
    const int c1 = ctr[1], c2 = ctr[2], c3 = ctr[3];
    const int fmt = (c1 > 0) ? 0 : ((c2 > 0 || c3 > 0) ? 2 : 1);

    for (int f = blockIdx.x * 4 + wv; f < count; f += gridDim.x * 4) {
        const int row = list[f];
        const float* hrow = hiddenR + (size_t)f * HD;
        float a20[NACT];
#pragma unroll
        for (int a = 0; a < NACT; ++a) a20[a] = 0.f;
#pragma unroll 4
        for (int m = 0; m < 16; ++m) {
            const int h = lane + 64 * m;
            const float hv = hrow[h];
            const float4* w4 = (const float4*)(W2 + (size_t)h * NACT);
            const float4 w0 = w4[0], w1 = w4[1], w2 = w4[2], w3 = w4[3], w4v = w4[4];
            a20[0]  = fmaf(hv, w0.x,  a20[0]);  a20[1]  = fmaf(hv, w0.y,  a20[1]);
            a20[2]  = fmaf(hv, w0.z,  a20[2]);  a20[3]  = fmaf(hv, w0.w,  a20[3]);
            a20[4]  = fmaf(hv, w1.x,  a20[4]);  a20[5]  = fmaf(hv, w1.y,  a20[5]);
            a20[6]  = fmaf(hv, w1.z,  a20[6]);  a20[7]  = fmaf(hv, w1.w,  a20[7]);
            a20[8]  = fmaf(hv, w2.x,  a20[8]);  a20[9]  = fmaf(hv, w2.y,  a20[9]);
            a20[10] = fmaf(hv, w2.z,  a20[10]); a20[11] = fmaf(hv, w2.w,  a20[11]);
            a20[12] = fmaf(hv, w3.x,  a20[12]); a20[13] = fmaf(hv, w3.y,  a20[13]);
            a20[14] = fmaf(hv, w3.z,  a20[14]); a20[15] = fmaf(hv, w3.w,  a20[15]);
            a20[16] = fmaf(hv, w4v.x, a20[16]); a20[17] = fmaf(hv, w4v.y, a20[17]);
            a20[18] = fmaf(hv, w4v.z, a20[18]); a20[19] = fmaf(hv, w4v.w, a20[19]);
        }
#pragma unroll
        for (int off = 32; off; off >>= 1) {
#pragma unroll
            for (int a = 0; a < NACT; ++a) a20[a] += __shfl_xor(a20[a], off, 64);
        }
        finish_row(a20, b2, mask, real_actions, fmt, row, out, nullptr, nullptr, lane);
    }
}

// ---------------- launcher ----------------
extern "C" void kernel_launch(void* const* d_in, const int* in_sizes, int n_in,
                              void* d_out, int out_size, void* d_ws, size_t ws_size,
                              hipStream_t stream)
{
    const float* buf_h = (const float*)d_in[0];
    const float* stk_h = (const float*)d_in[1];
    const float* out_h = (const float*)d_in[2];
    const float* act_h = (const float*)d_in[3];
    const float* W1    = (const float*)d_in[4];
    const float* b1    = (const float*)d_in[5];
    const float* W2    = (const float*)d_in[6];
    const float* b2    = (const float*)d_in[7];
    const void*  mask  = d_in[8];
    const int*   ra    = (const int*)d_in[9];
    float*       out   = (float*)d_out;

    int*  ctr      = (int*)d_ws;
    int*  flagList = (int*)((char*)d_ws + 256);
    char* Wp       = (char*)d_ws + 256 + 65536;
    const size_t wpBytes = (size_t)8 * KT_N * 16384;           // 16 MiB
    float* hidden  = (float*)(Wp + wpBytes);

    hipMemsetAsync(d_ws, 0, 256, stream);
    detect_mask_kernel<<<64, 256, 0, stream>>>(
        (const unsigned int*)mask, BTOT * NACT / 4, ctr);
    wpack_kernel<<<8 * KT_N, 256, 0, stream>>>(W1, Wp);

    hipFuncSetAttribute((const void*)gemm1_mfma_kernel,
                        hipFuncAttributeMaxDynamicSharedMemorySize, 131072);

    gemm1_mfma_kernel<<<256, 512, 131072, stream>>>(
        buf_h, stk_h, out_h, act_h, Wp, b1, hidden);
    head_kernel<<<BTOT / 8, 256, 0, stream>>>(
        hidden, W2, b2, mask, ra, ctr, flagList, out, 0);

    float* hiddenR = hidden;
    refine_hidden_kernel<<<2048, 256, 0, stream>>>(
        buf_h, stk_h, out_h, act_h, W1, b1, ctr, flagList, hiddenR, BTOT);
    refine_head_kernel<<<64, 256, 0, stream>>>(
        hiddenR, W2, b2, mask, ra, ctr, flagList, out, BTOT);
}